// Round 3
// baseline (302.475 us; speedup 1.0000x reference)
//
#include <hip/hip_runtime.h>
#include <stdint.h>

// ---------------------------------------------------------------------------
// EdgeNodeGCN on MI355X (gfx950). Inputs fp32, edge_index int32, output fp32.
// Factorization:
//   P[n]  = x[n] @ (Wa - Wb) + b_edge   (Wa = W_edge[0:128], Wb = W_edge[128:256])
//   Q[n]  = x[n] @ Wb
//   msg(e)= relu(P[dst] + Q[src]);  edge_agg[d] = sum msg
//   XA[d] = sum_{e->d} x[src]           (segment_sum commutes with @W_node)
//   nodes = relu(XA @ W_node + b_node); edges = relu(edge_agg @ W_ed + b_ed)
//   out   = sigmoid(relu([nodes|edges] @ W_f1 + b_f1) @ W_f2 + b_f2)
//
// R12 == R11 resubmit (R11 never ran: GPU acquisition timeout).
// R11 vs R10 (302 us): rocprof showed k_tail = 78 us with EVERYTHING idle
// (Mfma 3.6%, VALU 5.3%, HBM 3.2%, Occ 20.6%) -> latency-bound, no overlap:
// 50KB LDS capped occupancy at 3 blocks/CU, and one wave serially ran all 24
// col-chunks (~164 dependent global loads). Restructure:
//   - one block per 16-row tile (grid=row_tiles), 24 col-chunks SPLIT across
//     the 4 waves (4x shorter serial chain, 4x more loads in flight);
//   - LDS = single [16][392] tile (12.5KB) -> ~6 blocks/CU at VGPR~76;
//   - one barrier; wave 0 runs the tiny final MLP.
// Predicted: k_tail 78 -> ~20-25 us (Occ >60%), total ~245 us.
// Dispatches: convert, sg, gather, tail (4).
// ---------------------------------------------------------------------------

typedef short short8 __attribute__((ext_vector_type(8)));
typedef float f32x4 __attribute__((ext_vector_type(4)));
typedef float float4v __attribute__((ext_vector_type(4)));
typedef unsigned short us8 __attribute__((ext_vector_type(8)));
typedef unsigned short us4 __attribute__((ext_vector_type(4)));

__device__ inline float bf2f(unsigned short h) {
    union { unsigned int u; float f; } v;
    v.u = ((unsigned int)h) << 16;
    return v.f;
}
__device__ inline unsigned short f2bf(float f) {
    union { float f; unsigned int u; } v;
    v.f = f;
    unsigned int r = v.u + 0x7FFFu + ((v.u >> 16) & 1u);  // RNE
    return (unsigned short)(r >> 16);
}

// ---- convert x + weights(col-major) -> bf16; head[]=-1, deg[]=0 -----------
__global__ __launch_bounds__(256) void k_convert(
    const float* __restrict__ x, const float* __restrict__ W_edge,
    const float* __restrict__ W_node, const float* __restrict__ W_ed,
    const float* __restrict__ W_f1,
    unsigned short* __restrict__ xb, unsigned short* __restrict__ WE2T,
    unsigned short* __restrict__ WnT, unsigned short* __restrict__ WdT,
    unsigned short* __restrict__ Wf1T, int* __restrict__ head,
    int* __restrict__ deg,
    int quads, int N)
{
    int i = blockIdx.x * 256 + threadIdx.x;
    if (i < quads) {
        float4v v = ((const float4v*)x)[i];
        us4 o;
        for (int j = 0; j < 4; ++j) o[j] = f2bf(v[j]);
        ((us4*)xb)[i] = o;
        return;
    }
    int j = i - quads;
    if (j < 65536) {                          // WE2T [512 c][128 k] = [Wa-Wb|Wb]^T
        int c = j & 511, k = j >> 9;
        float v;
        if (c < 256) v = W_edge[k * 256 + c] - W_edge[(k + 128) * 256 + c];
        else         v = W_edge[(k + 128) * 256 + (c - 256)];
        WE2T[c * 128 + k] = f2bf(v);
    } else if (j < 65536 + 32768) {           // WnT [256 c][128 k]
        int t = j - 65536;
        int c = t & 255, k = t >> 8;
        WnT[c * 128 + k] = f2bf(W_node[k * 256 + c]);
    } else if (j < 65536 + 65536) {           // WdT [128 c][256 k]
        int t = j - 65536 - 32768;
        int c = t & 127, k = t >> 7;
        WdT[c * 256 + k] = f2bf(W_ed[k * 128 + c]);
    } else if (j < 143360) {                  // Wf1T [32 c][384 k]
        int t = j - 65536 - 65536;
        int c = t & 31, k = t >> 5;
        Wf1T[c * 384 + k] = f2bf(W_f1[k * 32 + c]);
    } else {
        int t = j - 143360;
        if (t < N) { head[t] = -1; deg[t] = 0; }
    }
}

// ---- fused dispatch: padded-CSR build (1/3 of blocks) + GEMM1 (2/3) -------
__global__ __launch_bounds__(512) void k_sg(
    const int* __restrict__ src, const int* __restrict__ dst,
    int* __restrict__ head, unsigned long long* __restrict__ next2,
    int* __restrict__ deg, int* __restrict__ adj,
    const unsigned short* __restrict__ xb,     // [N][128] bf16
    const unsigned short* __restrict__ WE2T,   // [512][128] bf16 col-major
    const float* __restrict__ b_edge,          // [256] fp32
    unsigned short* __restrict__ T,            // [N][512]
    int E, int N, int row_tiles, int scat_blocks, int gemm_blocks)
{
    __shared__ unsigned short st[2][16 * 132];
    int b = blockIdx.x;
    if (b % 3 == 2) {                          // scatter pass: padded CSR
        int sb_id = b / 3;
        if (sb_id >= scat_blocks) return;
        int i = sb_id * 512 + threadIdx.x;
        if (i >= E) return;
        int s = src[i], d = dst[i];
        if ((unsigned)d >= (unsigned)N || (unsigned)s >= (unsigned)N) return;
        int pos = atomicAdd(&deg[d], 1);
        if (pos < 32) {
            adj[(size_t)d * 32 + pos] = s;
        } else {                               // overflow: linked list
            int old = atomicExch(&head[d], i);
            next2[i] = ((unsigned long long)(unsigned)s << 32) | (unsigned)old;
        }
        return;
    }
    int g = b - b / 3;                         // gemm block id
    if (g >= gemm_blocks) return;
    int gx = g >> 2;                           // row group (8 tiles)
    int gy = g & 3;                            // col quarter (128 cols)

    const int lane = threadIdx.x & 63;
    const int wave = threadIdx.x >> 6;
    const int quad = lane >> 4;
    const int col16 = lane & 15;
    const int lcol = wave * 16 + col16;        // 0..127
    const int col = gy * 128 + lcol;           // 0..511

    float bias = (col < 256) ? b_edge[col] : 0.f;

    short8 bf[4];
    for (int ks = 0; ks < 4; ++ks)
        bf[ks] = *(const short8*)(WE2T + (size_t)col * 128 + ks * 32 + quad * 8);

    const int tid = threadIdx.x;
    const int srow = tid >> 5;                 // 0..15
    const int sc4 = (tid & 31) * 4;            // 0..124

    for (int t = 0; t < 8; ++t) {
        int tile = gx * 8 + t;
        if (tile >= row_tiles) break;          // block-uniform
        int r0 = tile * 16;
        f32x4 acc = {0.f, 0.f, 0.f, 0.f};
        const unsigned short* ap = xb + (size_t)(r0 + col16) * 128 + quad * 8;
        for (int ks = 0; ks < 4; ++ks) {
            short8 a = *(const short8*)(ap + ks * 32);
            acc = __builtin_amdgcn_mfma_f32_16x16x32_bf16(a, bf[ks], acc, 0, 0, 0);
        }
        unsigned short* sbuf = st[t & 1];
        for (int r = 0; r < 4; ++r)
            sbuf[(quad * 4 + r) * 132 + lcol] = f2bf(acc[r] + bias);
        __syncthreads();
        us4 v = *(const us4*)(sbuf + srow * 132 + sc4);
        *(us4*)(T + (size_t)(r0 + srow) * 512 + gy * 128 + sc4) = v;
    }
}

// ---- Gather: half-wave per node over padded-CSR adjacency -----------------
__global__ __launch_bounds__(256) void k_gather(
    unsigned short* __restrict__ T,          // [N][512]: P|Q -> EA over P
    const unsigned short* __restrict__ xb,   // [N][128]
    unsigned short* __restrict__ XA,         // [N][128]
    const int* __restrict__ deg,
    const int* __restrict__ adj,             // [N][32]
    const int* __restrict__ head,
    const unsigned long long* __restrict__ next2, int N)
{
    int wave = threadIdx.x >> 6;
    int lane = threadIdx.x & 63;
    int half = lane >> 5;
    int c = lane & 31;
    int n = blockIdx.x * 8 + wave * 2 + half;
    bool act = n < N;
    int nn = act ? n : N - 1;
    int c8 = c * 8, c4 = c * 4;

    us8 pv = *(const us8*)(T + (size_t)nn * 512 + c8);
    float p[8];
    for (int j = 0; j < 8; ++j) p[j] = bf2f(pv[j]);
    float aE[8] = {0, 0, 0, 0, 0, 0, 0, 0};
    float aX[4] = {0, 0, 0, 0};

    int dg = act ? deg[n] : 0;                 // uniform within half-wave
    int adjv = adj[(size_t)nn * 32 + c];       // one coalesced 4B/lane read
    int m = dg < 32 ? dg : 32;

    int k = 0;
    for (; k + 1 < m; k += 2) {                // 2-way unroll: independent loads
        int s0 = __shfl(adjv, k, 32);
        int s1 = __shfl(adjv, k + 1, 32);
        us8 q0 = *(const us8*)(T + (size_t)s0 * 512 + 256 + c8);
        us8 q1 = *(const us8*)(T + (size_t)s1 * 512 + 256 + c8);
        us4 x0 = *(const us4*)(xb + (size_t)s0 * 128 + c4);
        us4 x1 = *(const us4*)(xb + (size_t)s1 * 128 + c4);
        for (int j = 0; j < 8; ++j) {
            aE[j] += fmaxf(p[j] + bf2f(q0[j]), 0.f);
            aE[j] += fmaxf(p[j] + bf2f(q1[j]), 0.f);
        }
        for (int j = 0; j < 4; ++j)
            aX[j] += bf2f(x0[j]) + bf2f(x1[j]);
    }
    if (k < m) {
        int s0 = __shfl(adjv, k, 32);
        us8 q0 = *(const us8*)(T + (size_t)s0 * 512 + 256 + c8);
        us4 x0 = *(const us4*)(xb + (size_t)s0 * 128 + c4);
        for (int j = 0; j < 8; ++j) aE[j] += fmaxf(p[j] + bf2f(q0[j]), 0.f);
        for (int j = 0; j < 4; ++j) aX[j] += bf2f(x0[j]);
    }

    // Overflow fallback (deg > 32): walk residual linked list. For E/N=8
    // random graphs this never triggers; kept for correctness.
    int cur = (act && dg > 32) ? head[n] : -1;
    while (__any(cur >= 0)) {
        bool v = cur >= 0;
        int safe = v ? cur : 0;
        unsigned long long e2 = next2[safe];
        int s = (int)(e2 >> 32);
        float mm = v ? 1.f : 0.f;
        const unsigned short* tb = T + (size_t)s * 512;
        us8 qv = *(const us8*)(tb + 256 + c8);
        us4 xv = *(const us4*)(xb + (size_t)s * 128 + c4);
        for (int j = 0; j < 8; ++j)
            aE[j] += mm * fmaxf(p[j] + bf2f(qv[j]), 0.f);
        for (int j = 0; j < 4; ++j)
            aX[j] += mm * bf2f(xv[j]);
        cur = v ? (int)(unsigned)(e2 & 0xFFFFFFFFull) : -1;
    }

    if (act) {
        us8 ev;
        for (int j = 0; j < 8; ++j) ev[j] = f2bf(aE[j]);
        *(us8*)(T + (size_t)n * 512 + c8) = ev;       // EA over own P slot: safe
        us4 xo;
        for (int j = 0; j < 4; ++j) xo[j] = f2bf(aX[j]);
        *(us4*)(XA + (size_t)n * 128 + c4) = xo;
    }
}

// ---- Fused tail: nodes/edges GEMMs + final MLP + sigmoid ------------------
// One BLOCK per 16-row tile; 24 col-chunks split across the 4 waves; single
// LDS h-tile [16][392]; one barrier; wave 0 runs the final MLP.
__global__ __launch_bounds__(256) void k_tail(
    const unsigned short* __restrict__ T,    // EA in cols 0-255
    const unsigned short* __restrict__ XA,   // [N][128]
    const unsigned short* __restrict__ WnT,  // [256][128] col-major
    const unsigned short* __restrict__ WdT,  // [128][256] col-major
    const unsigned short* __restrict__ Wf1T, // [32][384] col-major
    const float* __restrict__ b_node, const float* __restrict__ b_ed,
    const float* __restrict__ b_f1, const float* __restrict__ W_f2,
    const float* __restrict__ b_f2,
    float* __restrict__ out, int N, int row_tiles)
{
    __shared__ unsigned short hs[16 * 392];
    const int wave = threadIdx.x >> 6;
    const int lane = threadIdx.x & 63;
    const int quad = lane >> 4;
    const int col16 = lane & 15;
    int tile = blockIdx.x;
    if (tile >= row_tiles) return;
    int r0 = tile * 16;

    int arow = r0 + col16;
    if (arow >= N) arow = N - 1;

    // --- node path: 16 col-chunks, wave w takes cs = w, w+4, w+8, w+12 ---
    short8 ax[4];
    {
        const unsigned short* xap = XA + (size_t)arow * 128 + quad * 8;
        for (int ks = 0; ks < 4; ++ks) ax[ks] = *(const short8*)(xap + ks * 32);
    }
    for (int ci = 0; ci < 4; ++ci) {
        int cs = wave + ci * 4;
        int col = cs * 16 + col16;
        const unsigned short* wp = WnT + (size_t)col * 128 + quad * 8;
        f32x4 acc = {0.f, 0.f, 0.f, 0.f};
        for (int ks = 0; ks < 4; ++ks) {
            short8 b = *(const short8*)(wp + ks * 32);
            acc = __builtin_amdgcn_mfma_f32_16x16x32_bf16(ax[ks], b, acc, 0, 0, 0);
        }
        float bias = b_node[col];
        for (int r = 0; r < 4; ++r)
            hs[(quad * 4 + r) * 392 + col] = f2bf(fmaxf(acc[r] + bias, 0.f));
    }

    // --- edge path: 8 col-chunks, wave w takes cs = w, w+4 ---
    short8 ae[8];
    {
        const unsigned short* eap = T + (size_t)arow * 512 + quad * 8;
        for (int ks = 0; ks < 8; ++ks) ae[ks] = *(const short8*)(eap + ks * 32);
    }
    for (int ci = 0; ci < 2; ++ci) {
        int cs = wave + ci * 4;
        int col = cs * 16 + col16;
        const unsigned short* wp = WdT + (size_t)col * 256 + quad * 8;
        f32x4 acc = {0.f, 0.f, 0.f, 0.f};
        for (int ks = 0; ks < 8; ++ks) {
            short8 b = *(const short8*)(wp + ks * 32);
            acc = __builtin_amdgcn_mfma_f32_16x16x32_bf16(ae[ks], b, acc, 0, 0, 0);
        }
        float bias = b_ed[col];
        for (int r = 0; r < 4; ++r)
            hs[(quad * 4 + r) * 392 + 256 + col] = f2bf(fmaxf(acc[r] + bias, 0.f));
    }

    __syncthreads();
    if (wave != 0) return;

    // --- final MLP on wave 0: [16][384] @ [384][32] -> 32 cols ---
    f32x4 acc0 = {0.f, 0.f, 0.f, 0.f}, acc1 = {0.f, 0.f, 0.f, 0.f};
    const unsigned short* hp = hs + col16 * 392;
    const unsigned short* wpa = Wf1T + (size_t)col16 * 384;
    const unsigned short* wpb = Wf1T + (size_t)(col16 + 16) * 384;
    for (int ks = 0; ks < 12; ++ks) {
        short8 a = *(const short8*)(hp + ks * 32 + quad * 8);
        short8 ba = *(const short8*)(wpa + ks * 32 + quad * 8);
        short8 bb = *(const short8*)(wpb + ks * 32 + quad * 8);
        acc0 = __builtin_amdgcn_mfma_f32_16x16x32_bf16(a, ba, acc0, 0, 0, 0);
        acc1 = __builtin_amdgcn_mfma_f32_16x16x32_bf16(a, bb, acc1, 0, 0, 0);
    }
    float f1a = b_f1[col16], f1b = b_f1[16 + col16];
    float w2a = W_f2[col16], w2b = W_f2[16 + col16];
    float b2 = b_f2[0];
    float s[4];
    for (int r = 0; r < 4; ++r)
        s[r] = fmaxf(acc0[r] + f1a, 0.f) * w2a + fmaxf(acc1[r] + f1b, 0.f) * w2b;
    for (int m = 1; m < 16; m <<= 1)
        for (int r = 0; r < 4; ++r) s[r] += __shfl_xor(s[r], m, 64);
    if (col16 == 0) {
        int orow = r0 + quad * 4;
        for (int r = 0; r < 4; ++r) {
            if (orow + r < N) {
                float v = s[r] + b2;
                out[orow + r] = 1.f / (1.f + __expf(-v));
            }
        }
    }
}

extern "C" void kernel_launch(void* const* d_in, const int* in_sizes, int n_in,
                              void* d_out, int out_size, void* d_ws, size_t ws_size,
                              hipStream_t stream) {
    const float* x      = (const float*)d_in[0];
    const int*   ei     = (const int*)d_in[1];
    // d_in[2] = e (unused)
    const float* W_node = (const float*)d_in[3];
    const float* b_node = (const float*)d_in[4];
    const float* W_edge = (const float*)d_in[5];
    const float* b_edge = (const float*)d_in[6];
    const float* W_ed   = (const float*)d_in[7];
    const float* b_ed   = (const float*)d_in[8];
    const float* W_f1   = (const float*)d_in[9];
    const float* b_f1   = (const float*)d_in[10];
    const float* W_f2   = (const float*)d_in[11];
    const float* b_f2   = (const float*)d_in[12];

    const int N = in_sizes[0] / 128;
    const int E = in_sizes[1] / 2;
    const int* src = ei;
    const int* dst = ei + E;

    char* ws = (char*)d_ws;
    size_t off = 0;
    auto alloc = [&](size_t bytes) { size_t o = off; off += (bytes + 255) & ~(size_t)255; return o; };
    unsigned short* xb   = (unsigned short*)(ws + alloc((size_t)N * 128 * 2));
    unsigned short* WE2T = (unsigned short*)(ws + alloc(512 * 128 * 2));
    unsigned short* WnT  = (unsigned short*)(ws + alloc(256 * 128 * 2));
    unsigned short* WdT  = (unsigned short*)(ws + alloc(128 * 256 * 2));
    unsigned short* Wf1T = (unsigned short*)(ws + alloc(32 * 384 * 2));
    unsigned short* T    = (unsigned short*)(ws + alloc((size_t)N * 512 * 2));
    unsigned short* XA   = (unsigned short*)(ws + alloc((size_t)N * 128 * 2));
    int* head            = (int*)(ws + alloc((size_t)N * 4));
    unsigned long long* next2 = (unsigned long long*)(ws + alloc((size_t)E * 8));
    int* deg             = (int*)(ws + alloc((size_t)N * 4));
    int* adj             = (int*)(ws + alloc((size_t)N * 32 * 4));

    const int row_tiles   = (N + 15) / 16;
    const int row_groups  = (row_tiles + 7) / 8;
    const int quads       = N * 128 / 4;
    const int conv_items  = quads + 143360 + N;
    const int scat_blocks = (E + 511) / 512;
    const int gemm_blocks = row_groups * 4;
    int grid3 = scat_blocks * 3;
    int need_g = ((gemm_blocks + 1) / 2) * 3;
    if (need_g > grid3) grid3 = need_g;

    k_convert<<<(conv_items + 255) / 256, 256, 0, stream>>>(
        x, W_edge, W_node, W_ed, W_f1, xb, WE2T, WnT, WdT, Wf1T, head, deg,
        quads, N);
    k_sg<<<grid3, 512, 0, stream>>>(
        src, dst, head, next2, deg, adj, xb, WE2T, b_edge, T, E, N, row_tiles,
        scat_blocks, gemm_blocks);
    k_gather<<<(N + 7) / 8, 256, 0, stream>>>(T, xb, XA, deg, adj, head, next2, N);
    k_tail<<<row_tiles, 256, 0, stream>>>(
        T, XA, WnT, WdT, Wf1T, b_node, b_ed, b_f1, W_f2, b_f2,
        (float*)d_out, N, row_tiles);
}

// Round 4
// 262.347 us; speedup vs baseline: 1.1530x; 1.1530x over previous
//
#include <hip/hip_runtime.h>
#include <stdint.h>

// ---------------------------------------------------------------------------
// EdgeNodeGCN on MI355X (gfx950). Inputs fp32, edge_index int32, output fp32.
// Factorization:
//   P[n]  = x[n] @ (Wa - Wb) + b_edge   (Wa = W_edge[0:128], Wb = W_edge[128:256])
//   Q[n]  = x[n] @ Wb
//   msg(e)= relu(P[dst] + Q[src]);  edge_agg[d] = sum msg
//   XA[d] = sum_{e->d} x[src]           (segment_sum commutes with @W_node)
//   nodes = relu(XA @ W_node + b_node); edges = relu(edge_agg @ W_ed + b_ed)
//   out   = sigmoid(relu([nodes|edges] @ W_f1 + b_f1) @ W_f2 + b_f2)
//
// R13 vs R12 (302 us, k_tail 83 us): R12 proved occupancy was NOT the issue
// (Occ 20->63%, dur 78->83). VGPR=32 + per-block weight re-read (475 MB, L2
// evicted by streaming T/XA -> L3 latency ~800cy) = ~60 SERIAL loads/wave.
// New k_tail: persistent-register weights, many tiles per block:
//   - 512 blocks x 4 waves, ~7 tiles each; B frags bn[4][4]+be[2][8]+bf[2][3]
//     loaded ONCE (~152 VGPR held, __launch_bounds__(256,2));
//   - per tile: 12 independent A loads + 38 reg-MFMA; per-wave h slice via
//     small LDS (C->A transpose, same-wave, no barrier);
//   - MLP: each wave partial over its OWN 96-K slice (Wf1 permuted to Wf1P in
//     k_convert so slices are contiguous); 4-wave reduce in padded LDS.
// Weight traffic 475 -> 78 MB. Predicted: k_tail 83 -> ~15-25 us, VGPR ~230,
// Occ ~25% (by design), total -> ~235 us. sg/gather untouched.
// Dispatches: convert, sg, gather, tail (4).
// ---------------------------------------------------------------------------

typedef short short8 __attribute__((ext_vector_type(8)));
typedef float f32x4 __attribute__((ext_vector_type(4)));
typedef float float4v __attribute__((ext_vector_type(4)));
typedef unsigned short us8 __attribute__((ext_vector_type(8)));
typedef unsigned short us4 __attribute__((ext_vector_type(4)));

__device__ inline float bf2f(unsigned short h) {
    union { unsigned int u; float f; } v;
    v.u = ((unsigned int)h) << 16;
    return v.f;
}
__device__ inline unsigned short f2bf(float f) {
    union { float f; unsigned int u; } v;
    v.f = f;
    unsigned int r = v.u + 0x7FFFu + ((v.u >> 16) & 1u);  // RNE
    return (unsigned short)(r >> 16);
}

// ---- convert x + weights(col-major) -> bf16; head[]=-1, deg[]=0 -----------
// Wf1P layout: [32 c][384 kp], kp = wave*96 + idx;
//   idx<64:  node chunk ci=idx>>4, korig = (wave+ci*4)*16 + (idx&15)
//   idx>=64: edge chunk ci=(idx-64)>>4, korig = 256 + (wave+ci*4)*16 + (idx&15)
__global__ __launch_bounds__(256) void k_convert(
    const float* __restrict__ x, const float* __restrict__ W_edge,
    const float* __restrict__ W_node, const float* __restrict__ W_ed,
    const float* __restrict__ W_f1,
    unsigned short* __restrict__ xb, unsigned short* __restrict__ WE2T,
    unsigned short* __restrict__ WnT, unsigned short* __restrict__ WdT,
    unsigned short* __restrict__ Wf1P, int* __restrict__ head,
    int* __restrict__ deg,
    int quads, int N)
{
    int i = blockIdx.x * 256 + threadIdx.x;
    if (i < quads) {
        float4v v = ((const float4v*)x)[i];
        us4 o;
        for (int j = 0; j < 4; ++j) o[j] = f2bf(v[j]);
        ((us4*)xb)[i] = o;
        return;
    }
    int j = i - quads;
    if (j < 65536) {                          // WE2T [512 c][128 k] = [Wa-Wb|Wb]^T
        int c = j & 511, k = j >> 9;
        float v;
        if (c < 256) v = W_edge[k * 256 + c] - W_edge[(k + 128) * 256 + c];
        else         v = W_edge[(k + 128) * 256 + (c - 256)];
        WE2T[c * 128 + k] = f2bf(v);
    } else if (j < 65536 + 32768) {           // WnT [256 c][128 k]
        int t = j - 65536;
        int c = t & 255, k = t >> 8;
        WnT[c * 128 + k] = f2bf(W_node[k * 256 + c]);
    } else if (j < 65536 + 65536) {           // WdT [128 c][256 k]
        int t = j - 65536 - 32768;
        int c = t & 127, k = t >> 7;
        WdT[c * 256 + k] = f2bf(W_ed[k * 128 + c]);
    } else if (j < 143360) {                  // Wf1P [32 c][384 kp] permuted
        int t = j - 65536 - 65536;
        int c = t & 31, kp = t >> 5;
        int w = kp / 96, idx = kp % 96;
        int korig;
        if (idx < 64) korig = (w + (idx >> 4) * 4) * 16 + (idx & 15);
        else          korig = 256 + (w + ((idx - 64) >> 4) * 4) * 16 + (idx & 15);
        Wf1P[c * 384 + kp] = f2bf(W_f1[korig * 32 + c]);
    } else {
        int t = j - 143360;
        if (t < N) { head[t] = -1; deg[t] = 0; }
    }
}

// ---- fused dispatch: padded-CSR build (1/3 of blocks) + GEMM1 (2/3) -------
__global__ __launch_bounds__(512) void k_sg(
    const int* __restrict__ src, const int* __restrict__ dst,
    int* __restrict__ head, unsigned long long* __restrict__ next2,
    int* __restrict__ deg, int* __restrict__ adj,
    const unsigned short* __restrict__ xb,     // [N][128] bf16
    const unsigned short* __restrict__ WE2T,   // [512][128] bf16 col-major
    const float* __restrict__ b_edge,          // [256] fp32
    unsigned short* __restrict__ T,            // [N][512]
    int E, int N, int row_tiles, int scat_blocks, int gemm_blocks)
{
    __shared__ unsigned short st[2][16 * 132];
    int b = blockIdx.x;
    if (b % 3 == 2) {                          // scatter pass: padded CSR
        int sb_id = b / 3;
        if (sb_id >= scat_blocks) return;
        int i = sb_id * 512 + threadIdx.x;
        if (i >= E) return;
        int s = src[i], d = dst[i];
        if ((unsigned)d >= (unsigned)N || (unsigned)s >= (unsigned)N) return;
        int pos = atomicAdd(&deg[d], 1);
        if (pos < 32) {
            adj[(size_t)d * 32 + pos] = s;
        } else {                               // overflow: linked list
            int old = atomicExch(&head[d], i);
            next2[i] = ((unsigned long long)(unsigned)s << 32) | (unsigned)old;
        }
        return;
    }
    int g = b - b / 3;                         // gemm block id
    if (g >= gemm_blocks) return;
    int gx = g >> 2;                           // row group (8 tiles)
    int gy = g & 3;                            // col quarter (128 cols)

    const int lane = threadIdx.x & 63;
    const int wave = threadIdx.x >> 6;
    const int quad = lane >> 4;
    const int col16 = lane & 15;
    const int lcol = wave * 16 + col16;        // 0..127
    const int col = gy * 128 + lcol;           // 0..511

    float bias = (col < 256) ? b_edge[col] : 0.f;

    short8 bf[4];
    for (int ks = 0; ks < 4; ++ks)
        bf[ks] = *(const short8*)(WE2T + (size_t)col * 128 + ks * 32 + quad * 8);

    const int tid = threadIdx.x;
    const int srow = tid >> 5;                 // 0..15
    const int sc4 = (tid & 31) * 4;            // 0..124

    for (int t = 0; t < 8; ++t) {
        int tile = gx * 8 + t;
        if (tile >= row_tiles) break;          // block-uniform
        int r0 = tile * 16;
        f32x4 acc = {0.f, 0.f, 0.f, 0.f};
        const unsigned short* ap = xb + (size_t)(r0 + col16) * 128 + quad * 8;
        for (int ks = 0; ks < 4; ++ks) {
            short8 a = *(const short8*)(ap + ks * 32);
            acc = __builtin_amdgcn_mfma_f32_16x16x32_bf16(a, bf[ks], acc, 0, 0, 0);
        }
        unsigned short* sbuf = st[t & 1];
        for (int r = 0; r < 4; ++r)
            sbuf[(quad * 4 + r) * 132 + lcol] = f2bf(acc[r] + bias);
        __syncthreads();
        us4 v = *(const us4*)(sbuf + srow * 132 + sc4);
        *(us4*)(T + (size_t)(r0 + srow) * 512 + gy * 128 + sc4) = v;
    }
}

// ---- Gather: half-wave per node over padded-CSR adjacency -----------------
__global__ __launch_bounds__(256) void k_gather(
    unsigned short* __restrict__ T,          // [N][512]: P|Q -> EA over P
    const unsigned short* __restrict__ xb,   // [N][128]
    unsigned short* __restrict__ XA,         // [N][128]
    const int* __restrict__ deg,
    const int* __restrict__ adj,             // [N][32]
    const int* __restrict__ head,
    const unsigned long long* __restrict__ next2, int N)
{
    int wave = threadIdx.x >> 6;
    int lane = threadIdx.x & 63;
    int half = lane >> 5;
    int c = lane & 31;
    int n = blockIdx.x * 8 + wave * 2 + half;
    bool act = n < N;
    int nn = act ? n : N - 1;
    int c8 = c * 8, c4 = c * 4;

    us8 pv = *(const us8*)(T + (size_t)nn * 512 + c8);
    float p[8];
    for (int j = 0; j < 8; ++j) p[j] = bf2f(pv[j]);
    float aE[8] = {0, 0, 0, 0, 0, 0, 0, 0};
    float aX[4] = {0, 0, 0, 0};

    int dg = act ? deg[n] : 0;                 // uniform within half-wave
    int adjv = adj[(size_t)nn * 32 + c];       // one coalesced 4B/lane read
    int m = dg < 32 ? dg : 32;

    int k = 0;
    for (; k + 1 < m; k += 2) {                // 2-way unroll: independent loads
        int s0 = __shfl(adjv, k, 32);
        int s1 = __shfl(adjv, k + 1, 32);
        us8 q0 = *(const us8*)(T + (size_t)s0 * 512 + 256 + c8);
        us8 q1 = *(const us8*)(T + (size_t)s1 * 512 + 256 + c8);
        us4 x0 = *(const us4*)(xb + (size_t)s0 * 128 + c4);
        us4 x1 = *(const us4*)(xb + (size_t)s1 * 128 + c4);
        for (int j = 0; j < 8; ++j) {
            aE[j] += fmaxf(p[j] + bf2f(q0[j]), 0.f);
            aE[j] += fmaxf(p[j] + bf2f(q1[j]), 0.f);
        }
        for (int j = 0; j < 4; ++j)
            aX[j] += bf2f(x0[j]) + bf2f(x1[j]);
    }
    if (k < m) {
        int s0 = __shfl(adjv, k, 32);
        us8 q0 = *(const us8*)(T + (size_t)s0 * 512 + 256 + c8);
        us4 x0 = *(const us4*)(xb + (size_t)s0 * 128 + c4);
        for (int j = 0; j < 8; ++j) aE[j] += fmaxf(p[j] + bf2f(q0[j]), 0.f);
        for (int j = 0; j < 4; ++j) aX[j] += bf2f(x0[j]);
    }

    // Overflow fallback (deg > 32): walk residual linked list.
    int cur = (act && dg > 32) ? head[n] : -1;
    while (__any(cur >= 0)) {
        bool v = cur >= 0;
        int safe = v ? cur : 0;
        unsigned long long e2 = next2[safe];
        int s = (int)(e2 >> 32);
        float mm = v ? 1.f : 0.f;
        const unsigned short* tb = T + (size_t)s * 512;
        us8 qv = *(const us8*)(tb + 256 + c8);
        us4 xv = *(const us4*)(xb + (size_t)s * 128 + c4);
        for (int j = 0; j < 8; ++j)
            aE[j] += mm * fmaxf(p[j] + bf2f(qv[j]), 0.f);
        for (int j = 0; j < 4; ++j)
            aX[j] += mm * bf2f(xv[j]);
        cur = v ? (int)(unsigned)(e2 & 0xFFFFFFFFull) : -1;
    }

    if (act) {
        us8 ev;
        for (int j = 0; j < 8; ++j) ev[j] = f2bf(aE[j]);
        *(us8*)(T + (size_t)n * 512 + c8) = ev;       // EA over own P slot: safe
        us4 xo;
        for (int j = 0; j < 4; ++j) xo[j] = f2bf(aX[j]);
        *(us4*)(XA + (size_t)n * 128 + c4) = xo;
    }
}

// ---- Fused tail: persistent-weight multi-tile blocks ----------------------
// 4 waves/block; wave w owns node chunks {w,w+4,w+8,w+12}, edge {w,w+4},
// and MLP K-slice [w*96, w*96+96) of the permuted Wf1P. B frags live in
// registers for the whole block; ~tiles_per_block tiles streamed per block.
__global__ __launch_bounds__(256, 2) void k_tail(
    const unsigned short* __restrict__ T,    // EA in cols 0-255
    const unsigned short* __restrict__ XA,   // [N][128]
    const unsigned short* __restrict__ WnT,  // [256 c][128 k] col-major
    const unsigned short* __restrict__ WdT,  // [128 c][256 k] col-major
    const unsigned short* __restrict__ Wf1P, // [32 c][384 kp] permuted
    const float* __restrict__ b_node, const float* __restrict__ b_ed,
    const float* __restrict__ b_f1, const float* __restrict__ W_f2,
    const float* __restrict__ b_f2,
    float* __restrict__ out, int N, int row_tiles, int tiles_per_block)
{
    __shared__ unsigned short hslice[4][16 * 100];  // per-wave h (bf16), pad 100
    __shared__ float red[4][16][33];                // MLP partials, pad 33
    const int wave = threadIdx.x >> 6;
    const int lane = threadIdx.x & 63;
    const int quad = lane >> 4;
    const int col16 = lane & 15;

    // ---- persistent B fragments (loaded once per block) ----
    short8 bn[4][4], be[2][8], bfr[2][3];
    float bias_n[4], bias_e[2];
#pragma unroll
    for (int ci = 0; ci < 4; ++ci) {
        int col = (wave + ci * 4) * 16 + col16;
        bias_n[ci] = b_node[col];
#pragma unroll
        for (int ks = 0; ks < 4; ++ks)
            bn[ci][ks] = *(const short8*)(WnT + (size_t)col * 128 + ks * 32 + quad * 8);
    }
#pragma unroll
    for (int ci = 0; ci < 2; ++ci) {
        int col = (wave + ci * 4) * 16 + col16;
        bias_e[ci] = b_ed[col];
#pragma unroll
        for (int ks = 0; ks < 8; ++ks)
            be[ci][ks] = *(const short8*)(WdT + (size_t)col * 256 + ks * 32 + quad * 8);
    }
#pragma unroll
    for (int cc = 0; cc < 2; ++cc) {
        int c = cc * 16 + col16;
#pragma unroll
        for (int ks = 0; ks < 3; ++ks)
            bfr[cc][ks] = *(const short8*)(Wf1P + (size_t)c * 384 + wave * 96 + ks * 32 + quad * 8);
    }

    unsigned short* hw = &hslice[wave][0];
    int t0 = blockIdx.x * tiles_per_block;
    int t1 = t0 + tiles_per_block;
    if (t1 > row_tiles) t1 = row_tiles;

    for (int tile = t0; tile < t1; ++tile) {
        int r0 = tile * 16;
        int arow = r0 + col16;
        if (arow >= N) arow = N - 1;

        // --- node path: h[:,0:256], this wave's 4 chunks ---
        short8 ax[4];
        {
            const unsigned short* xap = XA + (size_t)arow * 128 + quad * 8;
#pragma unroll
            for (int ks = 0; ks < 4; ++ks) ax[ks] = *(const short8*)(xap + ks * 32);
        }
#pragma unroll
        for (int ci = 0; ci < 4; ++ci) {
            f32x4 acc = {0.f, 0.f, 0.f, 0.f};
#pragma unroll
            for (int ks = 0; ks < 4; ++ks)
                acc = __builtin_amdgcn_mfma_f32_16x16x32_bf16(ax[ks], bn[ci][ks], acc, 0, 0, 0);
#pragma unroll
            for (int r = 0; r < 4; ++r)
                hw[(quad * 4 + r) * 100 + ci * 16 + col16] =
                    f2bf(fmaxf(acc[r] + bias_n[ci], 0.f));
        }

        // --- edge path: h[:,256:384], this wave's 2 chunks ---
        short8 ae[8];
        {
            const unsigned short* eap = T + (size_t)arow * 512 + quad * 8;
#pragma unroll
            for (int ks = 0; ks < 8; ++ks) ae[ks] = *(const short8*)(eap + ks * 32);
        }
#pragma unroll
        for (int ci = 0; ci < 2; ++ci) {
            f32x4 acc = {0.f, 0.f, 0.f, 0.f};
#pragma unroll
            for (int ks = 0; ks < 8; ++ks)
                acc = __builtin_amdgcn_mfma_f32_16x16x32_bf16(ae[ks], be[ci][ks], acc, 0, 0, 0);
#pragma unroll
            for (int r = 0; r < 4; ++r)
                hw[(quad * 4 + r) * 100 + 64 + ci * 16 + col16] =
                    f2bf(fmaxf(acc[r] + bias_e[ci], 0.f));
        }

        // --- MLP partial over own 96-K slice (same-wave LDS, no barrier) ---
        f32x4 m0 = {0.f, 0.f, 0.f, 0.f}, m1 = {0.f, 0.f, 0.f, 0.f};
#pragma unroll
        for (int ks = 0; ks < 3; ++ks) {
            short8 a = *(const short8*)(hw + col16 * 100 + ks * 32 + quad * 8);
            m0 = __builtin_amdgcn_mfma_f32_16x16x32_bf16(a, bfr[0][ks], m0, 0, 0, 0);
            m1 = __builtin_amdgcn_mfma_f32_16x16x32_bf16(a, bfr[1][ks], m1, 0, 0, 0);
        }
#pragma unroll
        for (int r = 0; r < 4; ++r) {
            red[wave][quad * 4 + r][col16] = m0[r];
            red[wave][quad * 4 + r][16 + col16] = m1[r];
        }
        __syncthreads();

        // --- final reduce + MLP2 + sigmoid on wave 0 ---
        if (wave == 0) {
            int row = col16, g = quad;          // each lane: 8 cols of one row
            float s = 0.f;
#pragma unroll
            for (int cc = 0; cc < 8; ++cc) {
                int col = g * 8 + cc;
                float v = red[0][row][col] + red[1][row][col] +
                          red[2][row][col] + red[3][row][col] + b_f1[col];
                s += fmaxf(v, 0.f) * W_f2[col];
            }
            s += __shfl_xor(s, 16, 64);
            s += __shfl_xor(s, 32, 64);
            if (g == 0 && r0 + row < N) {
                float v = s + b_f2[0];
                out[r0 + row] = 1.f / (1.f + __expf(-v));
            }
        }
        __syncthreads();   // red reused next tile
    }
}

extern "C" void kernel_launch(void* const* d_in, const int* in_sizes, int n_in,
                              void* d_out, int out_size, void* d_ws, size_t ws_size,
                              hipStream_t stream) {
    const float* x      = (const float*)d_in[0];
    const int*   ei     = (const int*)d_in[1];
    // d_in[2] = e (unused)
    const float* W_node = (const float*)d_in[3];
    const float* b_node = (const float*)d_in[4];
    const float* W_edge = (const float*)d_in[5];
    const float* b_edge = (const float*)d_in[6];
    const float* W_ed   = (const float*)d_in[7];
    const float* b_ed   = (const float*)d_in[8];
    const float* W_f1   = (const float*)d_in[9];
    const float* b_f1   = (const float*)d_in[10];
    const float* W_f2   = (const float*)d_in[11];
    const float* b_f2   = (const float*)d_in[12];

    const int N = in_sizes[0] / 128;
    const int E = in_sizes[1] / 2;
    const int* src = ei;
    const int* dst = ei + E;

    char* ws = (char*)d_ws;
    size_t off = 0;
    auto alloc = [&](size_t bytes) { size_t o = off; off += (bytes + 255) & ~(size_t)255; return o; };
    unsigned short* xb   = (unsigned short*)(ws + alloc((size_t)N * 128 * 2));
    unsigned short* WE2T = (unsigned short*)(ws + alloc(512 * 128 * 2));
    unsigned short* WnT  = (unsigned short*)(ws + alloc(256 * 128 * 2));
    unsigned short* WdT  = (unsigned short*)(ws + alloc(128 * 256 * 2));
    unsigned short* Wf1P = (unsigned short*)(ws + alloc(32 * 384 * 2));
    unsigned short* T    = (unsigned short*)(ws + alloc((size_t)N * 512 * 2));
    unsigned short* XA   = (unsigned short*)(ws + alloc((size_t)N * 128 * 2));
    int* head            = (int*)(ws + alloc((size_t)N * 4));
    unsigned long long* next2 = (unsigned long long*)(ws + alloc((size_t)E * 8));
    int* deg             = (int*)(ws + alloc((size_t)N * 4));
    int* adj             = (int*)(ws + alloc((size_t)N * 32 * 4));

    const int row_tiles   = (N + 15) / 16;
    const int row_groups  = (row_tiles + 7) / 8;
    const int quads       = N * 128 / 4;
    const int conv_items  = quads + 143360 + N;
    const int scat_blocks = (E + 511) / 512;
    const int gemm_blocks = row_groups * 4;
    int grid3 = scat_blocks * 3;
    int need_g = ((gemm_blocks + 1) / 2) * 3;
    if (need_g > grid3) grid3 = need_g;

    int tail_blocks = 512;
    if (tail_blocks > row_tiles) tail_blocks = row_tiles;
    int tpb = (row_tiles + tail_blocks - 1) / tail_blocks;

    k_convert<<<(conv_items + 255) / 256, 256, 0, stream>>>(
        x, W_edge, W_node, W_ed, W_f1, xb, WE2T, WnT, WdT, Wf1P, head, deg,
        quads, N);
    k_sg<<<grid3, 512, 0, stream>>>(
        src, dst, head, next2, deg, adj, xb, WE2T, b_edge, T, E, N, row_tiles,
        scat_blocks, gemm_blocks);
    k_gather<<<(N + 7) / 8, 256, 0, stream>>>(T, xb, XA, deg, adj, head, next2, N);
    k_tail<<<tail_blocks, 256, 0, stream>>>(
        T, XA, WnT, WdT, Wf1P, b_node, b_ed, b_f1, W_f2, b_f2,
        (float*)d_out, N, row_tiles, tpb);
}